// Round 12
// baseline (404.973 us; speedup 1.0000x reference)
//
#include <hip/hip_runtime.h>
#include <math.h>

// Problem constants (from reference)
#define BS     32
#define LQ     300
#define DM     256
#define NH     8
#define CH     32      // DM / NH
#define SUMP   16
#define LV     8500    // 80*80+40*40+20*20+10*10
#define MROWS  (BS*LQ) // 9600
#define NW     384     // 256 off cols + 128 attn cols

// ---------------------------------------------------------------------------
// Kernel 1: P = query @ [w_off | w_attn] + [b_off | b_attn]
// 128x128 tile, BK=16, 8x8 micro-tile as 2x2 blocks of 4x4. Each thread
// stages TWO A-rows (arow, arow+64) — R11 bug was staging only rows 0..63.
// Grid 75x3; col-tile boundary (n0=0/128/256) lands on the w_off|w_attn split.
// ---------------------------------------------------------------------------
__global__ __launch_bounds__(256) void gemm_off_attn(
    const float* __restrict__ A,        // 9600 x 256
    const float* __restrict__ Boff,     // 256 x 256
    const float* __restrict__ Batt,     // 256 x 128
    const float* __restrict__ bias_off, // 256
    const float* __restrict__ bias_att, // 128
    float* __restrict__ C)              // 9600 x 384
{
    __shared__ float As[16][132];  // [k][m], pitch 132 (16B-aligned rows)
    __shared__ float Bs[16][132];  // [k][n]

    const int tid = threadIdx.x;
    const int m0  = blockIdx.x * 128;
    const int n0  = blockIdx.y * 128;

    const float* Bp; int ldb, nb0; const float* biasp;
    if (n0 < 256) { Bp = Boff; ldb = 256; nb0 = n0;       biasp = bias_off + n0; }
    else          { Bp = Batt; ldb = 128; nb0 = n0 - 256; biasp = bias_att + (n0 - 256); }

    const int tx   = tid & 15;    // col quad
    const int ty   = tid >> 4;    // row quad
    const int arow = tid >> 2;    // A stage: row 0..63 (and +64)
    const int a4   = tid & 3;     // A stage: k-chunk (float4)
    const int brow = tid >> 4;    // B stage: k row 0..15
    const int b4   = tid & 15;    // B stage: col chunk (float4); also +16

    // acc[i][j]: row {ty*4+i | 64+ty*4+(i-4)}, col {tx*4+j | 64+tx*4+(j-4)}
    float acc[8][8] = {};

    for (int k0 = 0; k0 < 256; k0 += 16) {
        const float4 av  = *(const float4*)&A [(size_t)(m0 + arow)      * DM + k0 + a4 * 4];
        const float4 av2 = *(const float4*)&A [(size_t)(m0 + 64 + arow) * DM + k0 + a4 * 4];
        const float4 bv1 = *(const float4*)&Bp[(size_t)(k0 + brow) * ldb + nb0 + b4 * 4];
        const float4 bv2 = *(const float4*)&Bp[(size_t)(k0 + brow) * ldb + nb0 + (b4 + 16) * 4];
        __syncthreads();   // previous compute done before overwrite
        As[a4 * 4 + 0][arow] = av.x;
        As[a4 * 4 + 1][arow] = av.y;
        As[a4 * 4 + 2][arow] = av.z;
        As[a4 * 4 + 3][arow] = av.w;
        As[a4 * 4 + 0][64 + arow] = av2.x;
        As[a4 * 4 + 1][64 + arow] = av2.y;
        As[a4 * 4 + 2][64 + arow] = av2.z;
        As[a4 * 4 + 3][64 + arow] = av2.w;
        *(float4*)&Bs[brow][b4 * 4]        = bv1;
        *(float4*)&Bs[brow][(b4 + 16) * 4] = bv2;
        __syncthreads();

        #pragma unroll
        for (int k = 0; k < 16; ++k) {
            const float4 a0 = *(const float4*)&As[k][ty * 4];
            const float4 a1 = *(const float4*)&As[k][64 + ty * 4];
            const float4 b0 = *(const float4*)&Bs[k][tx * 4];
            const float4 b1 = *(const float4*)&Bs[k][64 + tx * 4];
            const float ar[8] = {a0.x, a0.y, a0.z, a0.w, a1.x, a1.y, a1.z, a1.w};
            const float br[8] = {b0.x, b0.y, b0.z, b0.w, b1.x, b1.y, b1.z, b1.w};
            #pragma unroll
            for (int i = 0; i < 8; ++i)
                #pragma unroll
                for (int j = 0; j < 8; ++j)
                    acc[i][j] = fmaf(ar[i], br[j], acc[i][j]);
        }
    }

    const float4 bias0 = *(const float4*)&biasp[tx * 4];
    const float4 bias1 = *(const float4*)&biasp[64 + tx * 4];
    const float bb[8] = {bias0.x, bias0.y, bias0.z, bias0.w,
                         bias1.x, bias1.y, bias1.z, bias1.w};
    #pragma unroll
    for (int i = 0; i < 8; ++i) {
        const int m = m0 + ((i < 4) ? (ty * 4 + i) : (64 + ty * 4 + (i - 4)));
        float4 o0, o1;
        o0.x = acc[i][0] + bb[0]; o0.y = acc[i][1] + bb[1];
        o0.z = acc[i][2] + bb[2]; o0.w = acc[i][3] + bb[3];
        o1.x = acc[i][4] + bb[4]; o1.y = acc[i][5] + bb[5];
        o1.z = acc[i][6] + bb[6]; o1.w = acc[i][7] + bb[7];
        *(float4*)&C[(size_t)m * NW + n0 + tx * 4]      = o0;
        *(float4*)&C[(size_t)m * NW + n0 + 64 + tx * 4] = o1;
    }
}

// ---------------------------------------------------------------------------
// Kernel 2: block-per-(b,q) cooperative two-phase sampler.  (unchanged)
// ---------------------------------------------------------------------------
__global__ __launch_bounds__(256) void ms_deform(
    const float* __restrict__ P,     // 9600 x 384 (off | attn-logits)
    const float* __restrict__ ref,   // 9600 x 4
    const float* __restrict__ value, // 32 x 8500 x 256
    float* __restrict__ out)         // 9600 x 256
{
    __shared__ float  s_P[384];
    __shared__ float4 s_ref;
    __shared__ float  s_data[128][10];

    // XCD-chunk swizzle: 9600 blocks, 8 XCDs, 1200 contiguous bq per XCD
    const int bid = blockIdx.x;
    const int bq  = (bid & 7) * 1200 + (bid >> 3);
    const int tid = threadIdx.x;
    const int b   = bq / LQ;

    if (tid < 96) ((float4*)s_P)[tid] = ((const float4*)(P + (size_t)bq * NW))[tid];
    if (tid == 96) s_ref = *(const float4*)&ref[(size_t)bq * 4];
    __syncthreads();

    const int Wd[4] = {80, 40, 20, 10};
    const int St[4] = {0, 6400, 8000, 8400};

    if (tid < 128) {
        const int h = tid >> 4, p = tid & 15, lvl = p >> 2;
        const float4 r = s_ref;
        const float lg = s_P[256 + h * 16 + p];
        float m = lg;
        #pragma unroll
        for (int mk = 1; mk <= 8; mk <<= 1) m = fmaxf(m, __shfl_xor(m, mk, 64));
        const float e = __expf(lg - m);
        float s = e;
        #pragma unroll
        for (int mk = 1; mk <= 8; mk <<= 1) s += __shfl_xor(s, mk, 64);
        const float wn = e / s;   // normalized softmax weight

        const float ox = s_P[h * 32 + p * 2], oy = s_P[h * 32 + p * 2 + 1];
        const int   W  = Wd[lvl];
        const float fW = (float)W;
        const float x  = (r.x + ox * r.z * 0.125f) * fW - 0.5f;
        const float y  = (r.y + oy * r.w * 0.125f) * fW - 0.5f;
        const float xf = floorf(x), yf = floorf(y);
        const float fx = x - xf,    fy = y - yf;
        const int ix0 = (int)xf, iy0 = (int)yf;
        const float xv0 = (ix0 >= 0     && ix0 < W)     ? 1.f : 0.f;
        const float xv1 = (ix0 + 1 < W)                 ? 1.f : 0.f;
        const float yv0 = (iy0 >= 0     && iy0 < W)     ? 1.f : 0.f;
        const float yv1 = (iy0 + 1 < W)                 ? 1.f : 0.f;
        const float xv1f = (ix0 + 1 >= 0) ? xv1 : 0.f;
        const float yv1f = (iy0 + 1 >= 0) ? yv1 : 0.f;

        const int ix0c = min(max(ix0, 0), W - 1);
        const int ix1c = min(max(ix0 + 1, 0), W - 1);
        const int iy0c = min(max(iy0, 0), W - 1);
        const int iy1c = min(max(iy0 + 1, 0), W - 1);
        const int base = St[lvl];
        const int hch  = h * CH;

        s_data[tid][0] = wn * (1.f - fx) * (1.f - fy) * xv0  * yv0;
        s_data[tid][1] = __int_as_float((base + iy0c * W + ix0c) * DM + hch);
        s_data[tid][2] = wn * fx         * (1.f - fy) * xv1f * yv0;
        s_data[tid][3] = __int_as_float((base + iy0c * W + ix1c) * DM + hch);
        s_data[tid][4] = wn * (1.f - fx) * fy         * xv0  * yv1f;
        s_data[tid][5] = __int_as_float((base + iy1c * W + ix0c) * DM + hch);
        s_data[tid][6] = wn * fx         * fy         * xv1f * yv1f;
        s_data[tid][7] = __int_as_float((base + iy1c * W + ix1c) * DM + hch);
    }
    __syncthreads();

    const int w    = tid >> 6;   // wave 0..3 -> heads {2w, 2w+1}
    const int lane = tid & 63;
    const int grp  = lane >> 3;  // gather slot within instruction (0..7)
    const int c4   = lane & 7;   // float4 chunk of the 32 head channels

    const int hp0     = w * 32 + (grp >> 2);
    const int corner2 = (grp & 3) * 2;

    const float* vbase = value + (size_t)b * LV * DM + c4 * 4;

    float4 accA = {0.f, 0.f, 0.f, 0.f};
    float4 accB = {0.f, 0.f, 0.f, 0.f};

    #pragma unroll
    for (int i = 0; i < 16; ++i) {
        const float2 wo = *(const float2*)&s_data[hp0 + 2 * i][corner2];
        const float4 v  = *(const float4*)&vbase[(size_t)__float_as_int(wo.y)];
        if (i < 8) {
            accA.x = fmaf(wo.x, v.x, accA.x); accA.y = fmaf(wo.x, v.y, accA.y);
            accA.z = fmaf(wo.x, v.z, accA.z); accA.w = fmaf(wo.x, v.w, accA.w);
        } else {
            accB.x = fmaf(wo.x, v.x, accB.x); accB.y = fmaf(wo.x, v.y, accB.y);
            accB.z = fmaf(wo.x, v.z, accB.z); accB.w = fmaf(wo.x, v.w, accB.w);
        }
    }

    #pragma unroll
    for (int mk = 8; mk <= 32; mk <<= 1) {
        accA.x += __shfl_xor(accA.x, mk, 64); accA.y += __shfl_xor(accA.y, mk, 64);
        accA.z += __shfl_xor(accA.z, mk, 64); accA.w += __shfl_xor(accA.w, mk, 64);
        accB.x += __shfl_xor(accB.x, mk, 64); accB.y += __shfl_xor(accB.y, mk, 64);
        accB.z += __shfl_xor(accB.z, mk, 64); accB.w += __shfl_xor(accB.w, mk, 64);
    }

    if (lane < 8) {
        *(float4*)&out[(size_t)bq * DM + (2 * w)     * CH + c4 * 4] = accA;
        *(float4*)&out[(size_t)bq * DM + (2 * w + 1) * CH + c4 * 4] = accB;
    }
}

// ---------------------------------------------------------------------------
extern "C" void kernel_launch(void* const* d_in, const int* in_sizes, int n_in,
                              void* d_out, int out_size, void* d_ws, size_t ws_size,
                              hipStream_t stream) {
    const float* query  = (const float*)d_in[0];
    const float* refpts = (const float*)d_in[1];
    const float* value  = (const float*)d_in[2];
    const float* w_off  = (const float*)d_in[3];
    const float* b_off  = (const float*)d_in[4];
    const float* w_attn = (const float*)d_in[5];
    const float* b_attn = (const float*)d_in[6];
    float* out = (float*)d_out;
    float* P   = (float*)d_ws;   // 9600*384 f32 = 14.7 MB scratch

    dim3 gg(MROWS / 128, NW / 128);   // 75 x 3
    gemm_off_attn<<<gg, 256, 0, stream>>>(query, w_off, w_attn, b_off, b_attn, P);

    // one block per (b,q); 8 heads handled by 4 waves (2 heads/wave)
    ms_deform<<<MROWS, 256, 0, stream>>>(P, refpts, value, out);
}